// Round 6
// baseline (1130.483 us; speedup 1.0000x reference)
//
#include <hip/hip_runtime.h>
#include <math.h>

#define B_    2
#define S_    2048
#define M_TOT 4096
#define DIM_  2048
#define NH_   16
#define QL_   1536
#define KVL_  512
#define QKN_  128
#define QKR_  64
#define VH_   128
#define QKH_  192
#define QSTR  3072      // NH_*QKH_

typedef short s16x8 __attribute__((ext_vector_type(8)));
typedef float f32x4 __attribute__((ext_vector_type(4)));
typedef unsigned short u16;
#define AS1 __attribute__((address_space(1)))
#define AS3 __attribute__((address_space(3)))

__device__ inline u16 f2bf(float f) {
    unsigned u = __float_as_uint(f);
    unsigned r = u + 0x7FFFu + ((u >> 16) & 1u);   // round-to-nearest-even
    return (u16)(r >> 16);
}
__device__ inline float bf2f(u16 h) { return __uint_as_float(((unsigned)h) << 16); }

__device__ __forceinline__ void ld_lds16(const u16* g, u16* l) {
    __builtin_amdgcn_global_load_lds((const AS1 unsigned*)g, (AS3 unsigned*)l, 16, 0, 0);
}
// Counted-vmcnt barriers (T4): retire exactly the chunk the NEXT phase needs,
// leave the newest (in-flight) chunk's loads outstanding. K chunk = 3 loads/
// thread, V chunk = 4. lgkmcnt(0) publishes ds_writes / orders shuffles.
#define BARW3 do { asm volatile("s_waitcnt vmcnt(3) lgkmcnt(0)" ::: "memory"); __builtin_amdgcn_s_barrier(); } while (0)
#define BARW4 do { asm volatile("s_waitcnt vmcnt(4) lgkmcnt(0)" ::: "memory"); __builtin_amdgcn_s_barrier(); } while (0)
#define BARW0 do { asm volatile("s_waitcnt vmcnt(0) lgkmcnt(0)" ::: "memory"); __builtin_amdgcn_s_barrier(); } while (0)
#define BARLG do { asm volatile("s_waitcnt lgkmcnt(0)" ::: "memory"); __builtin_amdgcn_s_barrier(); } while (0)

// ---------------------------------------------------------------------------
// m97-pattern bf16 MFMA GEMM (known good since round 2).
// ---------------------------------------------------------------------------
__global__ __launch_bounds__(256)
void gemm_bf16(const u16* __restrict__ A, const u16* __restrict__ Bm,
               const float* __restrict__ bias, void* __restrict__ Cv,
               int M, int N, int K, int ldA, int ldB, int ldC,
               long long sAz, long long sBz, long long sCz,
               float alpha, int outF32)
{
    __shared__ u16 As[128 * 32];
    __shared__ u16 Bs[128 * 32];
    const int tid = threadIdx.x;
    const int w = tid >> 6, l = tid & 63;
    const int m0 = blockIdx.y * 128, n0 = blockIdx.x * 128;
    const int z = blockIdx.z;
    const u16* Az = A + (size_t)z * sAz;
    const u16* Bz = Bm + (size_t)z * sBz;

    const int rin = l >> 2;
    const int cel = (l & 3) * 8;
    const int lane15 = l & 15, quad = l >> 4;
    const int wm = w & 1, wn = w >> 1;

    f32x4 acc[4][4] = {};

    for (int k0 = 0; k0 < K; k0 += 32) {
        __syncthreads();
        #pragma unroll
        for (int c = 0; c < 2; ++c) {
            const int chunk = w * 2 + c;
            const int rowA = m0 + chunk * 16 + rin;
            const u16* ga = Az + (size_t)rowA * ldA + k0 + cel;
            u16* la = &As[chunk * 512 + rin * 32 + cel];
            __builtin_amdgcn_global_load_lds((const AS1 unsigned*)ga, (AS3 unsigned*)la, 16, 0, 0);
            int rowB = n0 + chunk * 16 + rin;
            if (rowB > N - 1) rowB = N - 1;
            const u16* gb = Bz + (size_t)rowB * ldB + k0 + cel;
            u16* lb = &Bs[chunk * 512 + rin * 32 + cel];
            __builtin_amdgcn_global_load_lds((const AS1 unsigned*)gb, (AS3 unsigned*)lb, 16, 0, 0);
        }
        __syncthreads();
        s16x8 af[4], bf[4];
        #pragma unroll
        for (int i = 0; i < 4; ++i)
            af[i] = *(const s16x8*)&As[(wm * 64 + i * 16 + lane15) * 32 + quad * 8];
        #pragma unroll
        for (int i = 0; i < 4; ++i)
            bf[i] = *(const s16x8*)&Bs[(wn * 64 + i * 16 + lane15) * 32 + quad * 8];
        #pragma unroll
        for (int mi = 0; mi < 4; ++mi)
            #pragma unroll
            for (int ni = 0; ni < 4; ++ni)
                acc[mi][ni] = __builtin_amdgcn_mfma_f32_16x16x32_bf16(af[mi], bf[ni], acc[mi][ni], 0, 0, 0);
    }

    const int cmb = m0 + wm * 64, cnb = n0 + wn * 64;
    if (outF32) {
        float* C = (float*)Cv + (size_t)z * sCz;
        #pragma unroll
        for (int mi = 0; mi < 4; ++mi)
            #pragma unroll
            for (int ni = 0; ni < 4; ++ni) {
                const int nn = cnb + ni * 16 + lane15;
                if (nn < N) {
                    const float bv = bias ? bias[nn] : 0.f;
                    #pragma unroll
                    for (int r = 0; r < 4; ++r) {
                        const int mm = cmb + mi * 16 + quad * 4 + r;
                        C[(size_t)mm * ldC + nn] = acc[mi][ni][r] * alpha + bv;
                    }
                }
            }
    } else {
        u16* C = (u16*)Cv + (size_t)z * sCz;
        #pragma unroll
        for (int mi = 0; mi < 4; ++mi)
            #pragma unroll
            for (int ni = 0; ni < 4; ++ni) {
                const int nn = cnb + ni * 16 + lane15;
                if (nn < N) {
                    const float bv = bias ? bias[nn] : 0.f;
                    #pragma unroll
                    for (int r = 0; r < 4; ++r) {
                        const int mm = cmb + mi * 16 + quad * 4 + r;
                        C[(size_t)mm * ldC + nn] = f2bf(acc[mi][ni][r] * alpha + bv);
                    }
                }
            }
    }
}

// ---------------------------------------------------------------------------
// Flash v8: LDS-traffic cut + latency hiding at v5's barrier count.
// v7 post-mortem: counted-vmcnt ring worked but 17 phases/tile doubled
// barrier overhead (18 barriers x ~300cy convergence) -> 467us. v5 cost
// model: LDS pipe is the busiest (~16K of 28K cyc/tile: 896 b128 frag
// reads + 275KB DMA writes + shuffles). v8:
//  (1) Q -> REGISTERS: each wave holds its 32 q-rows x 576 dims as 36
//      MFMA A-frags (144 VGPR, static-indexed; loaded once from global).
//      Score af ds_reads vanish (576->288 b128/tile); 74.7KB LDS freed.
//  (2) 3-slot x 32KB ring with issue-ahead-2: v5's exact phase structure
//      (6 score phases of 96 dims = 3 loads/thr; 4 PV phases of 32t = 4
//      loads/thr; 10 data phases + 2 softmax barriers/tile). Phase p's
//      data issued at top of phase p-2 (>=2 phases ~1000cy latency
//      budget); end-of-phase wait is COUNTED (retire only phase p+1's
//      chunk): B(0..3)=vmcnt(3), B(4..7)=vmcnt(4), B(8,9)=vmcnt(3)
//      (tail 0/lgkm). slot(t,p) = (t+p)%3; reuse always >=3 phases
//      (>=1 barrier) after last read. Verified: B(4) outstanding =
//      K5(3)+V0(4), vmcnt(4) retires K5; B(8) = V3(4)+K0'(3), vmcnt(3)
//      retires V3.
// Softmax, XOR source-permute swizzle (sx8/qx8), XCD decode, epilogue:
// v5 verbatim. LDS: 98304(ring) + 17408(P) + 2560(misc) = 118272 B.
// VGPR ~250 (vf in halves of 4 to cap liveness) -> 2 waves/SIMD OK.
// Spill tripwire: WRITE_SIZE >> 65.5MB would indicate scratch spill.
// ---------------------------------------------------------------------------
__global__ __launch_bounds__(512)
void mla_flash(u16* __restrict__ Qp, const u16* __restrict__ Kcat,
               const u16* __restrict__ KVT)
{
    __shared__ u16 sRing[3 * 16384];         // 98304 B: 3 slots x 32KB
    __shared__ u16 sP[64 * 136];             // 17408 B
    __shared__ float sRm[64 * 4];            // per-row max partials (4 k-slices)
    __shared__ float sRs[64 * 4];            // per-row sum partials
    __shared__ float sM[64], sL[64];

    const int tid = threadIdx.x;
    const int w = tid >> 6, l = tid & 63;
    const int lane15 = l & 15, quad = l >> 4;
    const int wq = w & 1;                    // q-half (rows wq*32 ..)
    const int wk = w >> 1;                   // score k-slice / PV c-slice

    // --- XCD-aware decode (bijective over 1024): b pinned per XCD half ---
    const int flat = blockIdx.x;
    const int xcd  = flat & 7;
    const int slot = flat >> 3;              // 0..127
    const int b    = xcd >> 2;
    const int h    = (xcd & 3) * 4 + (slot & 3);
    const int qt   = 31 - (slot >> 2);       // heavy tiles first
    const int qs   = qt * 64;

    u16* Qrow = Qp + ((size_t)h * M_TOT + b * S_ + qs) * 576;
    const float scale = 0.07216878364870323f;  // 1/sqrt(192)
    const u16* Kb = Kcat + (size_t)b * S_ * 576;
    const u16* Vb = KVT + (size_t)b * 512 * S_;

    const int seg8 = (tid & 3) * 8;          // linear LDS dest segment
    const int sx8  = (((tid & 3) ^ ((tid >> 3) & 3)) * 8);   // permuted SRC segment
    const int qx8  = ((quad ^ ((lane15 >> 1) & 3)) * 8);     // permuted READ segment
    const int ktiles = (qs + 64 + 127) >> 7;

    // K phase j (dims j*96..+96): 3 sub-blocks [128 keys][32 dims], 3 ld/thr
    auto issueK = [&](int kt, int j, int so) {
        const int key = tid >> 2;
        const u16* g = Kb + (size_t)(kt + key) * 576 + j * 96 + sx8;
        u16* d = &sRing[so + key * 32 + seg8];
        ld_lds16(g, d);
        ld_lds16(g + 32, d + 4096);
        ld_lds16(g + 64, d + 8192);
    };
    // V phase tc (cols kt+tc*32..+32): 4 sub-blocks [128 c][32 t], 4 ld/thr
    auto issueV = [&](int kt, int tc, int so) {
        const int rl = tid >> 2;
        const u16* g = Vb + (size_t)rl * S_ + kt + tc * 32 + sx8;
        u16* d = &sRing[so + rl * 32 + seg8];
        ld_lds16(g, d);
        ld_lds16(g + (size_t)128 * S_, d + 4096);
        ld_lds16(g + (size_t)256 * S_, d + 8192);
        ld_lds16(g + (size_t)384 * S_, d + 12288);
    };

    // ---- prologue: Q -> registers (36 x 16B frags), then prefetch K0,K1 ----
    s16x8 afq[2][18];
    #pragma unroll
    for (int mi = 0; mi < 2; ++mi) {
        const u16* qsrc = Qrow + (size_t)(wq * 32 + mi * 16 + lane15) * 576 + quad * 8;
        #pragma unroll
        for (int c = 0; c < 18; ++c)
            afq[mi][c] = *(const s16x8*)&qsrc[c * 32];
    }
    issueK(0, 0, 0);                         // slot(t=0,p=0) = 0
    issueK(0, 1, 16384);                     // slot(t=0,p=1) = 1
    if (tid < 64) { sM[tid] = -1e30f; sL[tid] = 0.f; }
    BARW3;                                   // Q + K0 landed; K1 in flight

    f32x4 Oacc[2][8] = {};                   // rows wq*32+mi*16+...; cols wk*128+ci*16+...

    for (int t = 0; t < ktiles; ++t) {
        const int kt = t << 7;
        const int tb = t % 3;                // slot(t,p) = (tb+p)%3
        const bool hn = (t + 1 < ktiles);
        f32x4 Sacc[2][2] = {};

        // ---- score phases p=0..5 (96 dims each), issue phase p+2 ----
        #pragma unroll
        for (int p = 0; p < 6; ++p) {
            const int soI = ((tb + p + 2) % 3) * 16384;
            if (p < 4) issueK(kt, p + 2, soI);
            else       issueV(kt, p - 4, soI);     // p=4,5 -> V0,V1
            const u16* base = &sRing[((tb + p) % 3) * 16384];
            __builtin_amdgcn_s_setprio(1);
            #pragma unroll
            for (int kk = 0; kk < 3; ++kk) {
                s16x8 bf[2];
                #pragma unroll
                for (int ni = 0; ni < 2; ++ni)
                    bf[ni] = *(const s16x8*)&base[kk * 4096 + (wk * 32 + ni * 16 + lane15) * 32 + qx8];
                #pragma unroll
                for (int mi = 0; mi < 2; ++mi)
                    #pragma unroll
                    for (int ni = 0; ni < 2; ++ni)
                        Sacc[mi][ni] = __builtin_amdgcn_mfma_f32_16x16x32_bf16(afq[mi][p * 3 + kk], bf[ni], Sacc[mi][ni], 0, 0, 0);
            }
            __builtin_amdgcn_s_setprio(0);
            if (p < 4) { BARW3; } else { BARW4; }
        }

        // ---- softmax part 1: scale + causal mask + per-slice row max ----
        #pragma unroll
        for (int mi = 0; mi < 2; ++mi)
            #pragma unroll
            for (int r = 0; r < 4; ++r) {
                const int rowl = wq * 32 + mi * 16 + quad * 4 + r;
                const int rowg = qs + rowl;
                float mx = -1e30f;
                #pragma unroll
                for (int ni = 0; ni < 2; ++ni) {
                    const int colg = kt + wk * 32 + ni * 16 + lane15;
                    float v = Sacc[mi][ni][r] * scale;
                    v = (colg <= rowg) ? v : -1e30f;
                    Sacc[mi][ni][r] = v;
                    mx = fmaxf(mx, v);
                }
                #pragma unroll
                for (int sh = 1; sh < 16; sh <<= 1) mx = fmaxf(mx, __shfl_xor(mx, sh));
                if (lane15 == 0) sRm[rowl * 4 + wk] = mx;
            }
        BARLG;                               // (A): sRm visible

        // ---- part 2: m/alpha redundantly; P -> sP; rescale O; row sums ----
        float mn_[2][4], al_[2][4];
        #pragma unroll
        for (int mi = 0; mi < 2; ++mi)
            #pragma unroll
            for (int r = 0; r < 4; ++r) {
                const int rowl = wq * 32 + mi * 16 + quad * 4 + r;
                const f32x4 pm = *(const f32x4*)&sRm[rowl * 4];   // broadcast b128
                const float m_old = sM[rowl];
                const float mn = fmaxf(fmaxf(fmaxf(pm[0], pm[1]), fmaxf(pm[2], pm[3])), m_old);
                const float al = __expf(m_old - mn);
                mn_[mi][r] = mn; al_[mi][r] = al;
                float sum = 0.f;
                #pragma unroll
                for (int ni = 0; ni < 2; ++ni) {
                    const float p = __expf(Sacc[mi][ni][r] - mn);
                    sP[rowl * 136 + wk * 32 + ni * 16 + lane15] = f2bf(p);
                    sum += p;
                }
                #pragma unroll
                for (int ci = 0; ci < 8; ++ci) Oacc[mi][ci][r] *= al;
                #pragma unroll
                for (int sh = 1; sh < 16; sh <<= 1) sum += __shfl_xor(sum, sh);
                if (lane15 == 0) sRs[rowl * 4 + wk] = sum;
            }
        BARLG;                               // (C): sP + sRs visible

        // ---- part 3: designated lanes update per-row m/l ----
        if (wk == 0 && lane15 == 0) {
            #pragma unroll
            for (int mi = 0; mi < 2; ++mi)
                #pragma unroll
                for (int r = 0; r < 4; ++r) {
                    const int rowl = wq * 32 + mi * 16 + quad * 4 + r;
                    const f32x4 ps = *(const f32x4*)&sRs[rowl * 4];
                    sL[rowl] = sL[rowl] * al_[mi][r] + (ps[0] + ps[1] + ps[2] + ps[3]);
                    sM[rowl] = mn_[mi][r];
                }
        }

        // ---- PV phases p=6..9 (tc = p-6): issue V(tc+2) / next-tile K ----
        #pragma unroll
        for (int tc = 0; tc < 4; ++tc) {
            const int p = 6 + tc;
            const int soI = ((tb + p + 2) % 3) * 16384;
            if (tc < 2)       issueV(kt, tc + 2, soI);           // V2, V3
            else if (hn)      issueK(kt + 128, tc - 2, soI);     // K0', K1'
            const u16* base = &sRing[((tb + p) % 3) * 16384];
            s16x8 pf[2];
            #pragma unroll
            for (int mi = 0; mi < 2; ++mi)
                pf[mi] = *(const s16x8*)&sP[(wq * 32 + mi * 16 + lane15) * 136 + tc * 32 + quad * 8];
            // half A: ci 0..3 (cap vf liveness at 4 frags for VGPR budget)
            {
                s16x8 vf[4];
                #pragma unroll
                for (int ci = 0; ci < 4; ++ci) {
                    const int rl = wk * 128 + ci * 16 + lane15;
                    vf[ci] = *(const s16x8*)&base[(rl >> 7) * 4096 + (rl & 127) * 32 + qx8];
                }
                __builtin_amdgcn_s_setprio(1);
                #pragma unroll
                for (int mi = 0; mi < 2; ++mi)
                    #pragma unroll
                    for (int ci = 0; ci < 4; ++ci)
                        Oacc[mi][ci] = __builtin_amdgcn_mfma_f32_16x16x32_bf16(pf[mi], vf[ci], Oacc[mi][ci], 0, 0, 0);
                __builtin_amdgcn_s_setprio(0);
            }
            // half B: ci 4..7
            {
                s16x8 vf[4];
                #pragma unroll
                for (int ci = 0; ci < 4; ++ci) {
                    const int rl = wk * 128 + (ci + 4) * 16 + lane15;
                    vf[ci] = *(const s16x8*)&base[(rl >> 7) * 4096 + (rl & 127) * 32 + qx8];
                }
                __builtin_amdgcn_s_setprio(1);
                #pragma unroll
                for (int mi = 0; mi < 2; ++mi)
                    #pragma unroll
                    for (int ci = 0; ci < 4; ++ci)
                        Oacc[mi][ci + 4] = __builtin_amdgcn_mfma_f32_16x16x32_bf16(pf[mi], vf[ci], Oacc[mi][ci + 4], 0, 0, 0);
                __builtin_amdgcn_s_setprio(0);
            }
            if (tc < 2)      { BARW4; }
            else if (tc == 2){ if (hn) { BARW3; } else { BARW0; } }
            else             { if (hn) { BARW3; } else { BARLG; } }
        }
    }

    // ---- epilogue: O/l -> bf16, overwrite Qpack[..., 0:512] ----
    #pragma unroll
    for (int mi = 0; mi < 2; ++mi)
        #pragma unroll
        for (int r = 0; r < 4; ++r) {
            const int rowl = wq * 32 + mi * 16 + quad * 4 + r;
            const float inv = 1.f / sL[rowl];
            #pragma unroll
            for (int ci = 0; ci < 8; ++ci)
                Qrow[(size_t)rowl * 576 + wk * 128 + ci * 16 + lane15] =
                    f2bf(Oacc[mi][ci][r] * inv);
        }
}

// ---------------------------------------------------------------------------
__global__ __launch_bounds__(256)
void cast_f32_bf16(const float* __restrict__ src, u16* __restrict__ dst, int n)
{
    for (int i = blockIdx.x * 256 + threadIdx.x; i < n; i += gridDim.x * 256)
        dst[i] = f2bf(src[i]);
}

__global__ __launch_bounds__(256)
void prep_wbnT(const float* __restrict__ wkvb, u16* __restrict__ dst)
{
    int i = blockIdx.x * 256 + threadIdx.x;
    int h = i >> 16, rem = i & 65535, c = rem >> 7, d = rem & 127;
    dst[i] = f2bf(wkvb[(size_t)(h * 256 + d) * 512 + c]);
}

__global__ __launch_bounds__(256)
void prep_wbv(const float* __restrict__ wkvb, u16* __restrict__ dst)
{
    int i = blockIdx.x * 256 + threadIdx.x;
    int h = i >> 16, rem = i & 65535;
    dst[i] = f2bf(wkvb[(size_t)h * 131072 + 65536 + rem]);
}

__global__ __launch_bounds__(256)
void rmsnorm_bf16(u16* __restrict__ X, const float* __restrict__ w, int D)
{
    const int m = blockIdx.x;
    u16* x = X + (size_t)m * D;
    float ss = 0.f;
    for (int k = threadIdx.x; k < D; k += 256) { float v = bf2f(x[k]); ss += v * v; }
    __shared__ float red[256];
    red[threadIdx.x] = ss; __syncthreads();
    for (int s = 128; s > 0; s >>= 1) {
        if (threadIdx.x < s) red[threadIdx.x] += red[threadIdx.x + s];
        __syncthreads();
    }
    const float sc = rsqrtf(red[0] / (float)D + 1e-6f);
    for (int k = threadIdx.x; k < D; k += 256) x[k] = f2bf(bf2f(x[k]) * sc * w[k]);
}

// q (bf16, rows QSTR) -> rotate q_pe, write to Qpack[h][m][512:576]
__global__ __launch_bounds__(256)
void rope_q(const u16* __restrict__ q, const float* __restrict__ freqs, u16* __restrict__ Qp)
{
    const int idx = blockIdx.x * 256 + threadIdx.x;
    const int i = idx & 31, h = (idx >> 5) & 15, m = idx >> 9;
    const int s = m & (S_ - 1);
    const float c = freqs[(s * 32 + i) * 2], sn = freqs[(s * 32 + i) * 2 + 1];
    const u16* src = q + (size_t)m * QSTR + h * QKH_ + QKN_ + 2 * i;
    const float x0 = bf2f(src[0]), x1 = bf2f(src[1]);
    u16* dst = Qp + ((size_t)h * M_TOT + m) * 576 + 512 + 2 * i;
    dst[0] = f2bf(x0 * c - x1 * sn);
    dst[1] = f2bf(x1 * c + x0 * sn);
}

__global__ __launch_bounds__(256)
void kv_norm_rope(const u16* __restrict__ kva, const float* __restrict__ w,
                  const float* __restrict__ freqs, u16* __restrict__ Kcat)
{
    const int m = blockIdx.x, s = m & (S_ - 1);
    const u16* x = kva + (size_t)m * 576;
    float ss = 0.f;
    for (int k = threadIdx.x; k < 512; k += 256) { float v = bf2f(x[k]); ss += v * v; }
    __shared__ float red[256];
    red[threadIdx.x] = ss; __syncthreads();
    for (int st = 128; st > 0; st >>= 1) {
        if (threadIdx.x < st) red[threadIdx.x] += red[threadIdx.x + st];
        __syncthreads();
    }
    const float sc = rsqrtf(red[0] / 512.f + 1e-6f);
    for (int k = threadIdx.x; k < 512; k += 256)
        Kcat[(size_t)m * 576 + k] = f2bf(bf2f(x[k]) * sc * w[k]);
    if (threadIdx.x < 32) {
        const int i = threadIdx.x;
        const float c = freqs[(s * 32 + i) * 2], sn = freqs[(s * 32 + i) * 2 + 1];
        const float x0 = bf2f(x[512 + 2 * i]), x1 = bf2f(x[512 + 2 * i + 1]);
        Kcat[(size_t)m * 576 + 512 + 2 * i]     = f2bf(x0 * c - x1 * sn);
        Kcat[(size_t)m * 576 + 512 + 2 * i + 1] = f2bf(x1 * c + x0 * sn);
    }
}

__global__ __launch_bounds__(256)
void transpose_kv(const u16* __restrict__ Kcat, u16* __restrict__ KVT)
{
    __shared__ u16 t[64][65];
    const int s0 = blockIdx.x * 64, c0 = blockIdx.y * 64, b = blockIdx.z;
    #pragma unroll
    for (int i = 0; i < 16; ++i) {
        int id = i * 256 + threadIdx.x, r = id >> 6, c = id & 63;
        t[r][c] = Kcat[(size_t)(b * S_ + s0 + r) * 576 + c0 + c];
    }
    __syncthreads();
    #pragma unroll
    for (int i = 0; i < 16; ++i) {
        int id = i * 256 + threadIdx.x, r = id >> 6, c = id & 63;
        KVT[(size_t)(b * 512 + c0 + r) * S_ + s0 + c] = t[c][r];
    }
}

// ---------------------------------------------------------------------------
extern "C" void kernel_launch(void* const* d_in, const int* in_sizes, int n_in,
                              void* d_out, int out_size, void* d_ws, size_t ws_size,
                              hipStream_t stream)
{
    (void)in_sizes; (void)n_in; (void)out_size; (void)ws_size;
    const float* x         = (const float*)d_in[0];
    const float* freqs     = (const float*)d_in[1];
    const float* wq_a_w    = (const float*)d_in[4];
    const float* wq_a_b    = (const float*)d_in[5];
    const float* q_norm_w  = (const float*)d_in[6];
    const float* wq_b_w    = (const float*)d_in[7];
    const float* wq_b_b    = (const float*)d_in[8];
    const float* wkv_a_w   = (const float*)d_in[9];
    const float* wkv_a_b   = (const float*)d_in[10];
    const float* kv_norm_w = (const float*)d_in[11];
    const float* wkv_b_w   = (const float*)d_in[12];
    const float* wo_w      = (const float*)d_in[13];
    const float* wo_b      = (const float*)d_in[14];
    float* out = (float*)d_out;

    char* W = (char*)d_ws;
    u16* x_bf  = (u16*)(W + 0);
    u16* wqa   = (u16*)(W + 16777216);
    u16* wqb   = (u16*)(W + 23068672);
    u16* wkva  = (u16*)(W + 32505856);
    u16* wobf  = (u16*)(W + 34865152);
    u16* wbnT  = (u16*)(W + 43253760);
    u16* wbv   = (u16*)(W + 45350912);
    u16* q_a   = (u16*)(W + 47448064);
    u16* q     = (u16*)(W + 60030976);
    u16* kv_a  = (u16*)(W + 85196800);
    u16* Kcat  = (u16*)(W + 89915392);
    u16* KVT   = (u16*)(W + 94633984);
    u16* Qp    = (u16*)(W + 98828288);   // Qpack[h][4096][576]: q_abs|q_pe -> attn out
    u16* outh  = (u16*)(W + 174325760);

    const dim3 blk(256);

    // --- dtype prep ---
    cast_f32_bf16<<<2048, blk, 0, stream>>>(x, x_bf, M_TOT * DIM_);
    cast_f32_bf16<<<2048, blk, 0, stream>>>(wq_a_w, wqa, QL_ * DIM_);
    cast_f32_bf16<<<2048, blk, 0, stream>>>(wq_b_w, wqb, QSTR * QL_);
    cast_f32_bf16<<<2048, blk, 0, stream>>>(wkv_a_w, wkva, 576 * DIM_);
    cast_f32_bf16<<<2048, blk, 0, stream>>>(wo_w, wobf, DIM_ * DIM_);
    prep_wbnT<<<4096, blk, 0, stream>>>(wkv_b_w, wbnT);
    prep_wbv<<<4096, blk, 0, stream>>>(wkv_b_w, wbv);

    // --- q path ---
    gemm_bf16<<<dim3(12, 32, 1), blk, 0, stream>>>(x_bf, wqa, wq_a_b, q_a,
        M_TOT, QL_, DIM_, DIM_, DIM_, QL_, 0, 0, 0, 1.f, 0);
    rmsnorm_bf16<<<M_TOT, blk, 0, stream>>>(q_a, q_norm_w, QL_);
    gemm_bf16<<<dim3(24, 32, 1), blk, 0, stream>>>(q_a, wqb, wq_b_b, q,
        M_TOT, QSTR, QL_, QL_, QL_, QSTR, 0, 0, 0, 1.f, 0);
    rope_q<<<(M_TOT * NH_ * 32) / 256, blk, 0, stream>>>(q, freqs, Qp);

    // --- kv path ---
    gemm_bf16<<<dim3(5, 32, 1), blk, 0, stream>>>(x_bf, wkva, wkv_a_b, kv_a,
        M_TOT, 576, DIM_, DIM_, DIM_, 576, 0, 0, 0, 1.f, 0);
    kv_norm_rope<<<M_TOT, blk, 0, stream>>>(kv_a, kv_norm_w, freqs, Kcat);
    transpose_kv<<<dim3(32, 8, 2), blk, 0, stream>>>(Kcat, KVT);

    // --- q absorb: Qpack[h][m][0:512] = q_nope @ wkv_b[h,:128,:] ---
    gemm_bf16<<<dim3(4, 32, 16), blk, 0, stream>>>(q, wbnT, nullptr, Qp,
        M_TOT, 512, 128, QSTR, 128, 576, QKH_, 65536, (long long)M_TOT * 576, 1.f, 0);

    // --- fused flash attention v8 (Q in regs, 3-slot issue-ahead-2 ring) ---
    mla_flash<<<dim3(1024, 1, 1), dim3(512), 0, stream>>>(Qp, Kcat, KVT);

    // --- V projection: outh[m][h*128+d] = O[h][m][:] . wbv[h][d][:] ---
    gemm_bf16<<<dim3(1, 32, 16), blk, 0, stream>>>(Qp, wbv, nullptr, outh,
        M_TOT, VH_, 512, 576, 512, DIM_, (long long)M_TOT * 576, 65536, VH_, 1.f, 0);

    // --- output projection (fp32 out) ---
    gemm_bf16<<<dim3(16, 32, 1), blk, 0, stream>>>(outh, wobf, wo_b, out,
        M_TOT, DIM_, DIM_, DIM_, DIM_, DIM_, 0, 0, 0, 1.f, 1);
}